// Round 2
// baseline (2831.838 us; speedup 1.0000x reference)
//
#include <hip/hip_runtime.h>
#include <math.h>

// ---- problem constants ----
#define B_SZ   4
#define LSEQ   1024
#define DMODEL 512
#define DINNER 1024
#define DSTATE 16
#define DCONV  4
#define DTRANK 32
#define NLAYER 8
#define NROWS  (B_SZ*LSEQ)      // 4096
#define CHUNK  32
#define NCHUNK (LSEQ/CHUNK)     // 32

__device__ __forceinline__ float sigmoid_(float x){ return 1.f/(1.f+__expf(-x)); }

// ============================================================================
// Templated fp32 tiled GEMM, NT form: C[m,n] = sum_k A[m*lda+k] * B[n*ldb+k]
// EPI: 0 = store, 1 = softplus(v + bias[n]) store, 2 = atomicAdd (split-K)
// Thread grid 16x16; each thread computes TM x TN outputs.
// ============================================================================
template<int BM,int BN,int BK,int TM,int TN,int EPI,bool SPLIT>
__global__ __launch_bounds__(256) void gemm_nt(
    const float* __restrict__ A, int lda,
    const float* __restrict__ Bmat, int ldb,
    float* __restrict__ C, int ldc,
    int M, int N, int K, int ksl,
    const float* __restrict__ bias)
{
    __shared__ float As[BK][BM+4];
    __shared__ float Bs[BK][BN+4];
    const int tid = threadIdx.x;
    const int tx = tid & 15, ty = tid >> 4;     // 16x16 thread grid
    const int m0 = blockIdx.y * BM;
    const int n0 = blockIdx.x * BN;
    int k0 = 0, k1 = K;
    if (SPLIT) { k0 = blockIdx.z * ksl; k1 = k0 + ksl; }

    float acc[TM][TN];
#pragma unroll
    for (int i=0;i<TM;i++)
#pragma unroll
        for (int j=0;j<TN;j++) acc[i][j]=0.f;

    for (int kt=k0; kt<k1; kt+=BK) {
        // stage A tile (BM x BK), transposed into LDS (k-major)
        constexpr int AV = BM*BK/4/256;
#pragma unroll
        for (int v=0; v<AV; ++v) {
            int idx = tid + v*256;              // float4 index
            int row = idx / (BK/4);
            int kq  = idx % (BK/4);
            float4 val = *reinterpret_cast<const float4*>(&A[(long)(m0+row)*lda + kt + kq*4]);
            As[kq*4+0][row]=val.x; As[kq*4+1][row]=val.y;
            As[kq*4+2][row]=val.z; As[kq*4+3][row]=val.w;
        }
        constexpr int BV = BN*BK/4/256;
#pragma unroll
        for (int v=0; v<BV; ++v) {
            int idx = tid + v*256;
            int row = idx / (BK/4);
            int kq  = idx % (BK/4);
            float4 val = *reinterpret_cast<const float4*>(&Bmat[(long)(n0+row)*ldb + kt + kq*4]);
            Bs[kq*4+0][row]=val.x; Bs[kq*4+1][row]=val.y;
            Bs[kq*4+2][row]=val.z; Bs[kq*4+3][row]=val.w;
        }
        __syncthreads();
#pragma unroll
        for (int k=0;k<BK;k++){
            float a[TM], b[TN];
#pragma unroll
            for (int i=0;i<TM;i+=4)
                *reinterpret_cast<float4*>(&a[i]) = *reinterpret_cast<const float4*>(&As[k][ty*TM+i]);
#pragma unroll
            for (int j=0;j<TN;j+=4)
                *reinterpret_cast<float4*>(&b[j]) = *reinterpret_cast<const float4*>(&Bs[k][tx*TN+j]);
#pragma unroll
            for (int i=0;i<TM;i++)
#pragma unroll
                for (int j=0;j<TN;j++) acc[i][j] = fmaf(a[i],b[j],acc[i][j]);
        }
        __syncthreads();
    }

    // epilogue
#pragma unroll
    for (int i=0;i<TM;i++){
        int m = m0 + ty*TM + i;
        if (EPI==2) {
#pragma unroll
            for (int j=0;j<TN;j++) atomicAdd(&C[(long)m*ldc + n0 + tx*TN + j], acc[i][j]);
        } else {
#pragma unroll
            for (int j=0;j<TN;j+=4){
                int n = n0 + tx*TN + j;
                float4 o;
                float* po = &o.x;
#pragma unroll
                for (int q=0;q<4;q++){
                    float v = acc[i][j+q];
                    if (EPI==1) {
                        v += bias[n+q];
                        v = (v > 20.f) ? v : log1pf(__expf(v));   // softplus
                    }
                    po[q] = v;
                }
                *reinterpret_cast<float4*>(&C[(long)m*ldc + n]) = o;
            }
        }
    }
}

// ============================================================================
// causal depthwise conv (k=4, left pad 3) + bias + silu
// reads xin = xz[..., :DINNER], writes u (B,L,DINNER). 4 channels per thread.
// ============================================================================
__global__ __launch_bounds__(256) void conv_silu_k(
    const float* __restrict__ xz, const float* __restrict__ cw,
    const float* __restrict__ cb, float* __restrict__ u)
{
    int idx = blockIdx.x*256 + threadIdx.x;      // over NROWS * (DINNER/4)
    int d4  = idx & (DINNER/4 - 1);
    int row = idx >> 8;                          // b*L + t
    int t   = row & (LSEQ-1);

    float4 cbv = *reinterpret_cast<const float4*>(&cb[d4*4]);
    float acc[4] = {cbv.x, cbv.y, cbv.z, cbv.w};
    // cw[d][j], 4 channels' worth = 16 floats
    float4 cw0 = *reinterpret_cast<const float4*>(&cw[d4*16 + 0]);
    float4 cw1 = *reinterpret_cast<const float4*>(&cw[d4*16 + 4]);
    float4 cw2 = *reinterpret_cast<const float4*>(&cw[d4*16 + 8]);
    float4 cw3 = *reinterpret_cast<const float4*>(&cw[d4*16 +12]);
    const float* pw[4] = {&cw0.x, &cw1.x, &cw2.x, &cw3.x};

#pragma unroll
    for (int j=0;j<DCONV;j++){
        int tt = t - (DCONV-1) + j;
        if (tt < 0) continue;
        float4 xv = *reinterpret_cast<const float4*>(&xz[(long)(row-(DCONV-1)+j)*2*DINNER + d4*4]);
        acc[0] = fmaf(xv.x, pw[0][j], acc[0]);
        acc[1] = fmaf(xv.y, pw[1][j], acc[1]);
        acc[2] = fmaf(xv.z, pw[2][j], acc[2]);
        acc[3] = fmaf(xv.w, pw[3][j], acc[3]);
    }
    float4 o;
    o.x = acc[0]*sigmoid_(acc[0]);
    o.y = acc[1]*sigmoid_(acc[1]);
    o.z = acc[2]*sigmoid_(acc[2]);
    o.w = acc[3]*sigmoid_(acc[3]);
    *reinterpret_cast<float4*>(&u[(long)row*DINNER + d4*4]) = o;
}

// ============================================================================
// Chunked selective scan.
// h_t = exp(delta_t * A) * h_{t-1} + (delta_t*u_t) * B_t ;  y_t = <h_t, C_t>
// Diagonal A => chunk transition product = exp(A * sum(delta))  (exact).
// Phase A: per (b,chunk,d): local scan from h=0 -> local final state + sum(delta)
// Phase B: per (b,d,s): exclusive scan across chunks
// Phase C: replay chunk with true h_in; fuse +u*D, silu(z) gate; write over u.
// ============================================================================
__global__ __launch_bounds__(256) void scan_phaseA(
    const float* __restrict__ delta, const float* __restrict__ u,
    const float* __restrict__ dbc, const float* __restrict__ Alog,
    float* __restrict__ hst, float* __restrict__ sd)
{
    __shared__ float Bsh[CHUNK*DSTATE];
    int bx = blockIdx.x;
    int dblk = bx & 3;                 // DINNER/256 = 4
    int c    = (bx>>2) & (NCHUNK-1);
    int b    = bx >> 7;
    int d    = dblk*256 + threadIdx.x;

    for (int i = threadIdx.x; i < CHUNK*DSTATE; i += 256) {
        int tr = i >> 4, s = i & 15;
        Bsh[i] = dbc[(long)(b*LSEQ + c*CHUNK + tr)*64 + DTRANK + s];
    }
    __syncthreads();

    float As[DSTATE];
#pragma unroll
    for (int s=0;s<DSTATE;s++) As[s] = -__expf(Alog[d*DSTATE+s]);
    float h[DSTATE];
#pragma unroll
    for (int s=0;s<DSTATE;s++) h[s]=0.f;
    float sumd = 0.f;

    long base = (long)(b*LSEQ + c*CHUNK)*DINNER + d;
    for (int tt=0; tt<CHUNK; ++tt) {
        float dt = delta[base + (long)tt*DINNER];
        float ut = u[base + (long)tt*DINNER];
        sumd += dt;
        float du = dt*ut;
#pragma unroll
        for (int s=0;s<DSTATE;s++)
            h[s] = fmaf(__expf(As[s]*dt), h[s], du*Bsh[tt*DSTATE+s]);
    }
    long ho = ((long)((b*NCHUNK + c)*DINNER) + d)*DSTATE;
#pragma unroll
    for (int s=0;s<DSTATE;s+=4)
        *reinterpret_cast<float4*>(&hst[ho+s]) = make_float4(h[s],h[s+1],h[s+2],h[s+3]);
    sd[(b*NCHUNK+c)*DINNER + d] = sumd;
}

__global__ __launch_bounds__(256) void scan_phaseB(
    const float* __restrict__ Alog, const float* __restrict__ sd,
    float* __restrict__ hst)
{
    int flat = blockIdx.x*256 + threadIdx.x;    // B*DINNER*DSTATE = 65536
    int s = flat & 15;
    int d = (flat >> 4) & (DINNER-1);
    int b = flat >> 14;
    float As = -__expf(Alog[d*DSTATE+s]);
    float H = 0.f;
    for (int c=0; c<NCHUNK; ++c) {
        long o = ((long)((b*NCHUNK+c)*DINNER)+d)*DSTATE + s;
        float hl  = hst[o];
        float sdc = sd[(b*NCHUNK+c)*DINNER + d];
        hst[o] = H;                              // becomes h_in for chunk c
        H = fmaf(__expf(As*sdc), H, hl);
    }
}

__global__ __launch_bounds__(256) void scan_phaseC(
    const float* __restrict__ delta, float* __restrict__ u,   // u read, overwritten with gated y
    const float* __restrict__ dbc, const float* __restrict__ Alog,
    const float* __restrict__ hst, const float* __restrict__ xz,
    const float* __restrict__ Dsk)
{
    __shared__ float Bsh[CHUNK*DSTATE];
    __shared__ float Csh[CHUNK*DSTATE];
    int bx = blockIdx.x;
    int dblk = bx & 3;
    int c    = (bx>>2) & (NCHUNK-1);
    int b    = bx >> 7;
    int d    = dblk*256 + threadIdx.x;

    for (int i = threadIdx.x; i < CHUNK*DSTATE; i += 256) {
        int tr = i >> 4, s = i & 15;
        long ro = (long)(b*LSEQ + c*CHUNK + tr)*64;
        Bsh[i] = dbc[ro + DTRANK + s];
        Csh[i] = dbc[ro + DTRANK + DSTATE + s];
    }
    __syncthreads();

    float As[DSTATE];
#pragma unroll
    for (int s=0;s<DSTATE;s++) As[s] = -__expf(Alog[d*DSTATE+s]);
    float h[DSTATE];
    long ho = ((long)((b*NCHUNK + c)*DINNER) + d)*DSTATE;
#pragma unroll
    for (int s=0;s<DSTATE;s+=4){
        float4 hv = *reinterpret_cast<const float4*>(&hst[ho+s]);
        h[s]=hv.x; h[s+1]=hv.y; h[s+2]=hv.z; h[s+3]=hv.w;
    }
    float Dd = Dsk[d];

    long base = (long)(b*LSEQ + c*CHUNK)*DINNER + d;
    for (int tt=0; tt<CHUNK; ++tt) {
        float dt = delta[base + (long)tt*DINNER];
        float ut = u[base + (long)tt*DINNER];
        float du = dt*ut;
        float y = 0.f;
#pragma unroll
        for (int s=0;s<DSTATE;s++){
            h[s] = fmaf(__expf(As[s]*dt), h[s], du*Bsh[tt*DSTATE+s]);
            y = fmaf(h[s], Csh[tt*DSTATE+s], y);
        }
        y = fmaf(ut, Dd, y);
        float zv = xz[(long)(b*LSEQ + c*CHUNK + tt)*2*DINNER + DINNER + d];
        y *= zv * sigmoid_(zv);
        u[base + (long)tt*DINNER] = y;           // gated output, in place
    }
}

// ============================================================================
extern "C" void kernel_launch(void* const* d_in, const int* in_sizes, int n_in,
                              void* d_out, int out_size, void* d_ws, size_t ws_size,
                              hipStream_t stream)
{
    const float* x_in = (const float*)d_in[0];
    const float* Wi   = (const float*)d_in[1];
    const float* cw   = (const float*)d_in[2];
    const float* cb   = (const float*)d_in[3];
    const float* Wx   = (const float*)d_in[4];
    const float* Wdt  = (const float*)d_in[5];
    const float* bdt  = (const float*)d_in[6];
    const float* Alog = (const float*)d_in[7];
    const float* Dsk  = (const float*)d_in[8];
    const float* Wo   = (const float*)d_in[9];
    float* out = (float*)d_out;

    // workspace layout (floats): ~85.5 MB total
    float* ws   = (float*)d_ws;
    float* xz    = ws;                       // 4*1024*2048 = 8388608
    float* u     = xz   + 8388608;           // 4*1024*1024 = 4194304
    float* dbc   = u    + 4194304;           // 4*1024*64   = 262144
    float* delta = dbc  + 262144;            // 4194304
    float* hst   = delta+ 4194304;           // 4*32*1024*16= 2097152
    float* sd    = hst  + 2097152;           // 131072
    float* xbuf  = sd   + 131072;            // 4*1024*512  = 2097152

    for (int l=0; l<NLAYER; ++l) {
        const float* Wi_l  = Wi  + (long)l*2*DINNER*DMODEL;
        const float* cw_l  = cw  + (long)l*DINNER*DCONV;
        const float* cb_l  = cb  + (long)l*DINNER;
        const float* Wx_l  = Wx  + (long)l*(DTRANK+2*DSTATE)*DINNER;
        const float* Wdt_l = Wdt + (long)l*DINNER*DTRANK;
        const float* bdt_l = bdt + (long)l*DINNER;
        const float* Al_l  = Alog+ (long)l*DINNER*DSTATE;
        const float* Dsk_l = Dsk + (long)l*DINNER;
        const float* Wo_l  = Wo  + (long)l*DMODEL*DINNER;
        const float* src = (l==0) ? x_in : xbuf;
        float* dst = (l==NLAYER-1) ? out : xbuf;

        // 1) xz = x @ Wi^T   (4096 x 2048, K=512)  -> 512 blocks
        gemm_nt<128,128,16,8,8,0,false><<<dim3(2*DINNER/128, NROWS/128), 256, 0, stream>>>(
            src, DMODEL, Wi_l, DMODEL, xz, 2*DINNER, NROWS, 2*DINNER, DMODEL, 0, nullptr);

        // 2) u = silu(causal_dwconv(xin) + cb)
        conv_silu_k<<<NROWS*(DINNER/4)/256, 256, 0, stream>>>(xz, cw_l, cb_l, u);

        // 3) dbc = u @ Wx^T  (4096 x 64, K=1024) split-K=8 with atomics -> 512 blocks
        hipMemsetAsync(dbc, 0, 262144*sizeof(float), stream);
        gemm_nt<64,64,16,4,4,2,true><<<dim3(1, NROWS/64, 8), 256, 0, stream>>>(
            u, DINNER, Wx_l, DINNER, dbc, 64, NROWS, 64, DINNER, DINNER/8, nullptr);

        // 4) delta = softplus(dt @ Wdt^T + bdt)  (4096 x 1024, K=32) -> 512 blocks
        gemm_nt<128,64,16,8,4,1,false><<<dim3(DINNER/64, NROWS/128), 256, 0, stream>>>(
            dbc, 64, Wdt_l, DTRANK, delta, DINNER, NROWS, DINNER, DTRANK, 0, bdt_l);

        // 5-7) chunked selective scan + gate (output replaces u)
        scan_phaseA<<<B_SZ*NCHUNK*(DINNER/256), 256, 0, stream>>>(delta, u, dbc, Al_l, hst, sd);
        scan_phaseB<<<B_SZ*DINNER*DSTATE/256, 256, 0, stream>>>(Al_l, sd, hst);
        scan_phaseC<<<B_SZ*NCHUNK*(DINNER/256), 256, 0, stream>>>(delta, u, dbc, Al_l, hst, xz, Dsk_l);

        // 8) out = ygated @ Wo^T  (4096 x 512, K=1024) -> 256 blocks (1/CU)
        gemm_nt<128,64,16,8,4,0,false><<<dim3(DMODEL/64, NROWS/128), 256, 0, stream>>>(
            u, DINNER, Wo_l, DINNER, dst, DMODEL, NROWS, DMODEL, DINNER, 0, nullptr);
    }
}

// Round 4
// 2238.917 us; speedup vs baseline: 1.2648x; 1.2648x over previous
//
#include <hip/hip_runtime.h>
#include <math.h>

// ---- problem constants ----
#define B_SZ   4
#define LSEQ   1024
#define DMODEL 512
#define DINNER 1024
#define DSTATE 16
#define DCONV  4
#define DTRANK 32
#define NLAYER 8
#define NROWS  (B_SZ*LSEQ)      // 4096
#define CHUNK  32
#define NCHUNK (LSEQ/CHUNK)     // 32
#define KPAD   40               // 32 + 8 pad: 80B row stride -> <=2-way LDS conflicts

__device__ __forceinline__ float sigmoid_(float x){ return 1.f/(1.f+__expf(-x)); }

typedef __attribute__((ext_vector_type(8))) short bf16x8;
typedef __attribute__((ext_vector_type(4))) short shortx4;
typedef __attribute__((ext_vector_type(4))) float f32x4;

__device__ __forceinline__ short f2bf(float f){
    unsigned int u = __float_as_uint(f);
    u = (u + 0x7FFFu + ((u >> 16) & 1u)) >> 16;     // RNE
    return (short)u;
}
__device__ __forceinline__ float bf2f(short s){
    unsigned int u = ((unsigned int)(unsigned short)s) << 16;
    return __uint_as_float(u);
}

// ============================================================================
// MFMA bf16x2-split GEMM, NT: C[m,n] = sum_k A[m,k]*B[n,k], near-fp32 accuracy.
// BM=128 fixed, BK=32, 256 threads = 4 waves in 2x2; wave tile 64 x BN_/2.
// Each k-step: stage fp32->bf16(hi/lo) into padded LDS, then 16x16x32 MFMAs:
// acc += al*bh + ah*bl + ah*bh   (lo*lo dropped, ~2^-18 relative)
// ============================================================================
template<int BN_>
__global__ __launch_bounds__(256) void gemm_mfma_nt(
    const float* __restrict__ A, int lda,
    const float* __restrict__ Bt, int ldb,
    float* __restrict__ C, int ldc, int K)
{
    constexpr int NREP = BN_/32;         // 16-wide frags per wave in n
    constexpr int HN   = BN_/2;          // per-wave n extent
    __shared__ __align__(16) short Ah[128*KPAD];
    __shared__ __align__(16) short Al[128*KPAD];
    __shared__ __align__(16) short Bh[BN_*KPAD];
    __shared__ __align__(16) short Bl[BN_*KPAD];

    const int tid  = threadIdx.x;
    const int lane = tid & 63;
    const int wave = tid >> 6;
    const int wm = wave >> 1, wn = wave & 1;
    const int m0 = blockIdx.y * 128;
    const int n0 = blockIdx.x * BN_;
    const int fr = lane & 15;            // frag row (A) / col (B,C)
    const int fg = lane >> 4;            // k-group (operands) / row-group (C)

    f32x4 acc[4][NREP];
#pragma unroll
    for (int m=0;m<4;m++)
#pragma unroll
        for (int n=0;n<NREP;n++) acc[m][n] = (f32x4)0.f;

    for (int kt = 0; kt < K; kt += 32) {
        // ---- stage A tile (128 x 32) with split conversion ----
#pragma unroll
        for (int v=0; v<4; ++v) {
            int idx = tid + v*256;
            int r   = idx >> 3;
            int k4  = (idx & 7) * 4;
            float4 x = *reinterpret_cast<const float4*>(&A[(long)(m0+r)*lda + kt + k4]);
            shortx4 hi, lo;
            hi.x=f2bf(x.x); lo.x=f2bf(x.x-bf2f(hi.x));
            hi.y=f2bf(x.y); lo.y=f2bf(x.y-bf2f(hi.y));
            hi.z=f2bf(x.z); lo.z=f2bf(x.z-bf2f(hi.z));
            hi.w=f2bf(x.w); lo.w=f2bf(x.w-bf2f(hi.w));
            *reinterpret_cast<shortx4*>(&Ah[r*KPAD + k4]) = hi;
            *reinterpret_cast<shortx4*>(&Al[r*KPAD + k4]) = lo;
        }
        // ---- stage B tile (BN_ x 32) ----
#pragma unroll
        for (int v=0; v<BN_/32; ++v) {
            int idx = tid + v*256;
            int r   = idx >> 3;
            int k4  = (idx & 7) * 4;
            float4 x = *reinterpret_cast<const float4*>(&Bt[(long)(n0+r)*ldb + kt + k4]);
            shortx4 hi, lo;
            hi.x=f2bf(x.x); lo.x=f2bf(x.x-bf2f(hi.x));
            hi.y=f2bf(x.y); lo.y=f2bf(x.y-bf2f(hi.y));
            hi.z=f2bf(x.z); lo.z=f2bf(x.z-bf2f(hi.z));
            hi.w=f2bf(x.w); lo.w=f2bf(x.w-bf2f(hi.w));
            *reinterpret_cast<shortx4*>(&Bh[r*KPAD + k4]) = hi;
            *reinterpret_cast<shortx4*>(&Bl[r*KPAD + k4]) = lo;
        }
        __syncthreads();

        bf16x8 bh[NREP], bl[NREP];
#pragma unroll
        for (int n=0;n<NREP;n++){
            int row = wn*HN + n*16 + fr;
            bh[n] = *reinterpret_cast<const bf16x8*>(&Bh[row*KPAD + fg*8]);
            bl[n] = *reinterpret_cast<const bf16x8*>(&Bl[row*KPAD + fg*8]);
        }
#pragma unroll
        for (int m=0;m<4;m++){
            int row = wm*64 + m*16 + fr;
            bf16x8 ah = *reinterpret_cast<const bf16x8*>(&Ah[row*KPAD + fg*8]);
            bf16x8 al = *reinterpret_cast<const bf16x8*>(&Al[row*KPAD + fg*8]);
#pragma unroll
            for (int n=0;n<NREP;n++){
                acc[m][n] = __builtin_amdgcn_mfma_f32_16x16x32_bf16(al, bh[n], acc[m][n], 0,0,0);
                acc[m][n] = __builtin_amdgcn_mfma_f32_16x16x32_bf16(ah, bl[n], acc[m][n], 0,0,0);
                acc[m][n] = __builtin_amdgcn_mfma_f32_16x16x32_bf16(ah, bh[n], acc[m][n], 0,0,0);
            }
        }
        __syncthreads();
    }

    // ---- epilogue: C[m0+wm*64+m*16+fg*4+q][n0+wn*HN+n*16+fr] ----
#pragma unroll
    for (int m=0;m<4;m++){
#pragma unroll
        for (int n=0;n<NREP;n++){
#pragma unroll
            for (int q=0;q<4;q++){
                int row = m0 + wm*64 + m*16 + fg*4 + q;
                int col = n0 + wn*HN + n*16 + fr;
                C[(long)row*ldc + col] = acc[m][n][q];
            }
        }
    }
}

// ============================================================================
// fp32 tiled GEMM (kept for the two small GEMMs), NT form.
// EPI: 0 = store, 1 = softplus(v + bias[n]) store, 2 = atomicAdd (split-K)
// ============================================================================
template<int BM,int BN,int BK,int TM,int TN,int EPI,bool SPLIT>
__global__ __launch_bounds__(256) void gemm_nt(
    const float* __restrict__ A, int lda,
    const float* __restrict__ Bmat, int ldb,
    float* __restrict__ C, int ldc,
    int M, int N, int K, int ksl,
    const float* __restrict__ bias)
{
    __shared__ float As[BK][BM+4];
    __shared__ float Bs[BK][BN+4];
    const int tid = threadIdx.x;
    const int tx = tid & 15, ty = tid >> 4;
    const int m0 = blockIdx.y * BM;
    const int n0 = blockIdx.x * BN;
    int k0 = 0, k1 = K;
    if (SPLIT) { k0 = blockIdx.z * ksl; k1 = k0 + ksl; }

    float acc[TM][TN];
#pragma unroll
    for (int i=0;i<TM;i++)
#pragma unroll
        for (int j=0;j<TN;j++) acc[i][j]=0.f;

    for (int kt=k0; kt<k1; kt+=BK) {
        constexpr int AV = BM*BK/4/256;
#pragma unroll
        for (int v=0; v<AV; ++v) {
            int idx = tid + v*256;
            int row = idx / (BK/4);
            int kq  = idx % (BK/4);
            float4 val = *reinterpret_cast<const float4*>(&A[(long)(m0+row)*lda + kt + kq*4]);
            As[kq*4+0][row]=val.x; As[kq*4+1][row]=val.y;
            As[kq*4+2][row]=val.z; As[kq*4+3][row]=val.w;
        }
        constexpr int BV = BN*BK/4/256;
#pragma unroll
        for (int v=0; v<BV; ++v) {
            int idx = tid + v*256;
            int row = idx / (BK/4);
            int kq  = idx % (BK/4);
            float4 val = *reinterpret_cast<const float4*>(&Bmat[(long)(n0+row)*ldb + kt + kq*4]);
            Bs[kq*4+0][row]=val.x; Bs[kq*4+1][row]=val.y;
            Bs[kq*4+2][row]=val.z; Bs[kq*4+3][row]=val.w;
        }
        __syncthreads();
#pragma unroll
        for (int k=0;k<BK;k++){
            float a[TM], b[TN];
#pragma unroll
            for (int i=0;i<TM;i+=4)
                *reinterpret_cast<float4*>(&a[i]) = *reinterpret_cast<const float4*>(&As[k][ty*TM+i]);
#pragma unroll
            for (int j=0;j<TN;j+=4)
                *reinterpret_cast<float4*>(&b[j]) = *reinterpret_cast<const float4*>(&Bs[k][tx*TN+j]);
#pragma unroll
            for (int i=0;i<TM;i++)
#pragma unroll
                for (int j=0;j<TN;j++) acc[i][j] = fmaf(a[i],b[j],acc[i][j]);
        }
        __syncthreads();
    }

#pragma unroll
    for (int i=0;i<TM;i++){
        int m = m0 + ty*TM + i;
        if (EPI==2) {
#pragma unroll
            for (int j=0;j<TN;j++) atomicAdd(&C[(long)m*ldc + n0 + tx*TN + j], acc[i][j]);
        } else {
#pragma unroll
            for (int j=0;j<TN;j+=4){
                int n = n0 + tx*TN + j;
                float4 o;
                float* po = &o.x;
#pragma unroll
                for (int q=0;q<4;q++){
                    float v = acc[i][j+q];
                    if (EPI==1) {
                        v += bias[n+q];
                        v = (v > 20.f) ? v : log1pf(__expf(v));
                    }
                    po[q] = v;
                }
                *reinterpret_cast<float4*>(&C[(long)m*ldc + n]) = o;
            }
        }
    }
}

// ============================================================================
// causal depthwise conv (k=4, left pad 3) + bias + silu
// ============================================================================
__global__ __launch_bounds__(256) void conv_silu_k(
    const float* __restrict__ xz, const float* __restrict__ cw,
    const float* __restrict__ cb, float* __restrict__ u)
{
    int idx = blockIdx.x*256 + threadIdx.x;
    int d4  = idx & (DINNER/4 - 1);
    int row = idx >> 8;
    int t   = row & (LSEQ-1);

    float4 cbv = *reinterpret_cast<const float4*>(&cb[d4*4]);
    float acc[4] = {cbv.x, cbv.y, cbv.z, cbv.w};
    float4 cw0 = *reinterpret_cast<const float4*>(&cw[d4*16 + 0]);
    float4 cw1 = *reinterpret_cast<const float4*>(&cw[d4*16 + 4]);
    float4 cw2 = *reinterpret_cast<const float4*>(&cw[d4*16 + 8]);
    float4 cw3 = *reinterpret_cast<const float4*>(&cw[d4*16 +12]);
    const float* pw[4] = {&cw0.x, &cw1.x, &cw2.x, &cw3.x};

#pragma unroll
    for (int j=0;j<DCONV;j++){
        int tt = t - (DCONV-1) + j;
        if (tt < 0) continue;
        float4 xv = *reinterpret_cast<const float4*>(&xz[(long)(row-(DCONV-1)+j)*2*DINNER + d4*4]);
        acc[0] = fmaf(xv.x, pw[0][j], acc[0]);
        acc[1] = fmaf(xv.y, pw[1][j], acc[1]);
        acc[2] = fmaf(xv.z, pw[2][j], acc[2]);
        acc[3] = fmaf(xv.w, pw[3][j], acc[3]);
    }
    float4 o;
    o.x = acc[0]*sigmoid_(acc[0]);
    o.y = acc[1]*sigmoid_(acc[1]);
    o.z = acc[2]*sigmoid_(acc[2]);
    o.w = acc[3]*sigmoid_(acc[3]);
    *reinterpret_cast<float4*>(&u[(long)row*DINNER + d4*4]) = o;
}

// ============================================================================
// Chunked selective scan (3 phases) — unchanged, validated round 2.
// ============================================================================
__global__ __launch_bounds__(256) void scan_phaseA(
    const float* __restrict__ delta, const float* __restrict__ u,
    const float* __restrict__ dbc, const float* __restrict__ Alog,
    float* __restrict__ hst, float* __restrict__ sd)
{
    __shared__ float Bsh[CHUNK*DSTATE];
    int bx = blockIdx.x;
    int dblk = bx & 3;
    int c    = (bx>>2) & (NCHUNK-1);
    int b    = bx >> 7;
    int d    = dblk*256 + threadIdx.x;

    for (int i = threadIdx.x; i < CHUNK*DSTATE; i += 256) {
        int tr = i >> 4, s = i & 15;
        Bsh[i] = dbc[(long)(b*LSEQ + c*CHUNK + tr)*64 + DTRANK + s];
    }
    __syncthreads();

    float As[DSTATE];
#pragma unroll
    for (int s=0;s<DSTATE;s++) As[s] = -__expf(Alog[d*DSTATE+s]);
    float h[DSTATE];
#pragma unroll
    for (int s=0;s<DSTATE;s++) h[s]=0.f;
    float sumd = 0.f;

    long base = (long)(b*LSEQ + c*CHUNK)*DINNER + d;
    for (int tt=0; tt<CHUNK; ++tt) {
        float dt = delta[base + (long)tt*DINNER];
        float ut = u[base + (long)tt*DINNER];
        sumd += dt;
        float du = dt*ut;
#pragma unroll
        for (int s=0;s<DSTATE;s++)
            h[s] = fmaf(__expf(As[s]*dt), h[s], du*Bsh[tt*DSTATE+s]);
    }
    long ho = ((long)((b*NCHUNK + c)*DINNER) + d)*DSTATE;
#pragma unroll
    for (int s=0;s<DSTATE;s+=4)
        *reinterpret_cast<float4*>(&hst[ho+s]) = make_float4(h[s],h[s+1],h[s+2],h[s+3]);
    sd[(b*NCHUNK+c)*DINNER + d] = sumd;
}

__global__ __launch_bounds__(256) void scan_phaseB(
    const float* __restrict__ Alog, const float* __restrict__ sd,
    float* __restrict__ hst)
{
    int flat = blockIdx.x*256 + threadIdx.x;
    int s = flat & 15;
    int d = (flat >> 4) & (DINNER-1);
    int b = flat >> 14;
    float As = -__expf(Alog[d*DSTATE+s]);
    float H = 0.f;
    for (int c=0; c<NCHUNK; ++c) {
        long o = ((long)((b*NCHUNK+c)*DINNER)+d)*DSTATE + s;
        float hl  = hst[o];
        float sdc = sd[(b*NCHUNK+c)*DINNER + d];
        hst[o] = H;
        H = fmaf(__expf(As*sdc), H, hl);
    }
}

__global__ __launch_bounds__(256) void scan_phaseC(
    const float* __restrict__ delta, float* __restrict__ u,
    const float* __restrict__ dbc, const float* __restrict__ Alog,
    const float* __restrict__ hst, const float* __restrict__ xz,
    const float* __restrict__ Dsk)
{
    __shared__ float Bsh[CHUNK*DSTATE];
    __shared__ float Csh[CHUNK*DSTATE];
    int bx = blockIdx.x;
    int dblk = bx & 3;
    int c    = (bx>>2) & (NCHUNK-1);
    int b    = bx >> 7;
    int d    = dblk*256 + threadIdx.x;

    for (int i = threadIdx.x; i < CHUNK*DSTATE; i += 256) {
        int tr = i >> 4, s = i & 15;
        long ro = (long)(b*LSEQ + c*CHUNK + tr)*64;
        Bsh[i] = dbc[ro + DTRANK + s];
        Csh[i] = dbc[ro + DTRANK + DSTATE + s];
    }
    __syncthreads();

    float As[DSTATE];
#pragma unroll
    for (int s=0;s<DSTATE;s++) As[s] = -__expf(Alog[d*DSTATE+s]);
    float h[DSTATE];
    long ho = ((long)((b*NCHUNK + c)*DINNER) + d)*DSTATE;
#pragma unroll
    for (int s=0;s<DSTATE;s+=4){
        float4 hv = *reinterpret_cast<const float4*>(&hst[ho+s]);
        h[s]=hv.x; h[s+1]=hv.y; h[s+2]=hv.z; h[s+3]=hv.w;
    }
    float Dd = Dsk[d];

    long base = (long)(b*LSEQ + c*CHUNK)*DINNER + d;
    for (int tt=0; tt<CHUNK; ++tt) {
        float dt = delta[base + (long)tt*DINNER];
        float ut = u[base + (long)tt*DINNER];
        float du = dt*ut;
        float y = 0.f;
#pragma unroll
        for (int s=0;s<DSTATE;s++){
            h[s] = fmaf(__expf(As[s]*dt), h[s], du*Bsh[tt*DSTATE+s]);
            y = fmaf(h[s], Csh[tt*DSTATE+s], y);
        }
        y = fmaf(ut, Dd, y);
        float zv = xz[(long)(b*LSEQ + c*CHUNK + tt)*2*DINNER + DINNER + d];
        y *= zv * sigmoid_(zv);
        u[base + (long)tt*DINNER] = y;
    }
}

// ============================================================================
extern "C" void kernel_launch(void* const* d_in, const int* in_sizes, int n_in,
                              void* d_out, int out_size, void* d_ws, size_t ws_size,
                              hipStream_t stream)
{
    const float* x_in = (const float*)d_in[0];
    const float* Wi   = (const float*)d_in[1];
    const float* cw   = (const float*)d_in[2];
    const float* cb   = (const float*)d_in[3];
    const float* Wx   = (const float*)d_in[4];
    const float* Wdt  = (const float*)d_in[5];
    const float* bdt  = (const float*)d_in[6];
    const float* Alog = (const float*)d_in[7];
    const float* Dsk  = (const float*)d_in[8];
    const float* Wo   = (const float*)d_in[9];
    float* out = (float*)d_out;

    float* ws   = (float*)d_ws;
    float* xz    = ws;                       // 8388608
    float* u     = xz   + 8388608;           // 4194304
    float* dbc   = u    + 4194304;           // 262144
    float* delta = dbc  + 262144;            // 4194304
    float* hst   = delta+ 4194304;           // 2097152
    float* sd    = hst  + 2097152;           // 131072
    float* xbuf  = sd   + 131072;            // 2097152

    for (int l=0; l<NLAYER; ++l) {
        const float* Wi_l  = Wi  + (long)l*2*DINNER*DMODEL;
        const float* cw_l  = cw  + (long)l*DINNER*DCONV;
        const float* cb_l  = cb  + (long)l*DINNER;
        const float* Wx_l  = Wx  + (long)l*(DTRANK+2*DSTATE)*DINNER;
        const float* Wdt_l = Wdt + (long)l*DINNER*DTRANK;
        const float* bdt_l = bdt + (long)l*DINNER;
        const float* Al_l  = Alog+ (long)l*DINNER*DSTATE;
        const float* Dsk_l = Dsk + (long)l*DINNER;
        const float* Wo_l  = Wo  + (long)l*DMODEL*DINNER;
        const float* src = (l==0) ? x_in : xbuf;
        float* dst = (l==NLAYER-1) ? out : xbuf;

        // 1) xz = x @ Wi^T   (4096 x 2048, K=512)  MFMA bf16x2, 512 blocks
        gemm_mfma_nt<128><<<dim3(2*DINNER/128, NROWS/128), 256, 0, stream>>>(
            src, DMODEL, Wi_l, DMODEL, xz, 2*DINNER, DMODEL);

        // 2) u = silu(causal_dwconv(xin) + cb)
        conv_silu_k<<<NROWS*(DINNER/4)/256, 256, 0, stream>>>(xz, cw_l, cb_l, u);

        // 3) dbc = u @ Wx^T  (4096 x 64, K=1024) split-K=8 fp32
        hipMemsetAsync(dbc, 0, 262144*sizeof(float), stream);
        gemm_nt<64,64,16,4,4,2,true><<<dim3(1, NROWS/64, 8), 256, 0, stream>>>(
            u, DINNER, Wx_l, DINNER, dbc, 64, NROWS, 64, DINNER, DINNER/8, nullptr);

        // 4) delta = softplus(dt @ Wdt^T + bdt)  (4096 x 1024, K=32) fp32
        gemm_nt<128,64,16,8,4,1,false><<<dim3(DINNER/64, NROWS/128), 256, 0, stream>>>(
            dbc, 64, Wdt_l, DTRANK, delta, DINNER, NROWS, DINNER, DTRANK, 0, bdt_l);

        // 5-7) chunked selective scan + gate (output replaces u)
        scan_phaseA<<<B_SZ*NCHUNK*(DINNER/256), 256, 0, stream>>>(delta, u, dbc, Al_l, hst, sd);
        scan_phaseB<<<B_SZ*DINNER*DSTATE/256, 256, 0, stream>>>(Al_l, sd, hst);
        scan_phaseC<<<B_SZ*NCHUNK*(DINNER/256), 256, 0, stream>>>(delta, u, dbc, Al_l, hst, xz, Dsk_l);

        // 8) out = ygated @ Wo^T  (4096 x 512, K=1024)  MFMA bf16x2, 256 blocks
        gemm_mfma_nt<64><<<dim3(DMODEL/64, NROWS/128), 256, 0, stream>>>(
            u, DINNER, Wo_l, DINNER, dst, DMODEL, DINNER);
    }
}

// Round 5
// 1699.872 us; speedup vs baseline: 1.6659x; 1.3171x over previous
//
#include <hip/hip_runtime.h>
#include <math.h>

// ---- problem constants ----
#define B_SZ   4
#define LSEQ   1024
#define DMODEL 512
#define DINNER 1024
#define DSTATE 16
#define DCONV  4
#define DTRANK 32
#define NLAYER 8
#define NROWS  (B_SZ*LSEQ)      // 4096
#define CHUNK  32
#define NCHUNK (LSEQ/CHUNK)     // 32
#define KPAD   40               // 32 + 8 pad shorts: 80B row stride

__device__ __forceinline__ float sigmoid_(float x){ return 1.f/(1.f+__expf(-x)); }

typedef __attribute__((ext_vector_type(8))) short bf16x8;
typedef __attribute__((ext_vector_type(4))) short shortx4;
typedef __attribute__((ext_vector_type(4))) float f32x4;

__device__ __forceinline__ short f2bf(float f){
    unsigned int u = __float_as_uint(f);
    u = (u + 0x7FFFu + ((u >> 16) & 1u)) >> 16;     // RNE
    return (short)u;
}
__device__ __forceinline__ float bf2f(short s){
    unsigned int u = ((unsigned int)(unsigned short)s) << 16;
    return __uint_as_float(u);
}

// ============================================================================
// fp32 -> (hi, lo) bf16 split, elementwise. n must be multiple of 1024.
// ============================================================================
__global__ __launch_bounds__(256) void split_k(
    const float* __restrict__ in, short* __restrict__ hi, short* __restrict__ lo)
{
    long i = ((long)blockIdx.x*256 + threadIdx.x)*4;
    float4 x = *reinterpret_cast<const float4*>(&in[i]);
    shortx4 h, l;
    h.x=f2bf(x.x); l.x=f2bf(x.x-bf2f(h.x));
    h.y=f2bf(x.y); l.y=f2bf(x.y-bf2f(h.y));
    h.z=f2bf(x.z); l.z=f2bf(x.z-bf2f(h.z));
    h.w=f2bf(x.w); l.w=f2bf(x.w-bf2f(h.w));
    *reinterpret_cast<shortx4*>(&hi[i]) = h;
    *reinterpret_cast<shortx4*>(&lo[i]) = l;
}

// ============================================================================
// MFMA GEMM on pre-split bf16 hi/lo operands, NT: C[m,n]=sum_k A[m,k]B[n,k].
// 4 waves (2x2); wave tile (BM/2)x(BN/2); BK=32; register-prefetch dbuf.
// acc += al*bh + ah*bl + ah*bh  (Markidis split, lo*lo dropped)
// EPI 0: fp32 store to C.  EPI 1: split bf16 store to Ch/Cl.
// ============================================================================
template<int BM,int BN,int EPI>
__global__ __launch_bounds__(256,4) void gemm_bs_nt(
    const short* __restrict__ Agh, const short* __restrict__ Agl, int lda,
    const short* __restrict__ Bgh, const short* __restrict__ Bgl, int ldb,
    float* __restrict__ C, int ldc,
    short* __restrict__ Ch, short* __restrict__ Cl, int K)
{
    constexpr int MREP = BM/32;
    constexpr int NREP = BN/32;
    constexpr int ACH  = BM/64;          // 16B chunks per thread per A array
    constexpr int BCH  = BN/64;
    __shared__ __align__(16) short Ahs[BM*KPAD], Als[BM*KPAD];
    __shared__ __align__(16) short Bhs[BN*KPAD], Bls[BN*KPAD];

    const int tid  = threadIdx.x;
    const int lane = tid & 63;
    const int wave = tid >> 6;
    const int wm = wave >> 1, wn = wave & 1;
    const int m0 = blockIdx.y * BM, n0 = blockIdx.x * BN;
    const int fr = lane & 15, fg = lane >> 4;

    int ar[ACH], ak[ACH];
#pragma unroll
    for (int j=0;j<ACH;j++){ int c = tid + j*256; ar[j]=c>>2; ak[j]=(c&3)*8; }
    int br[BCH], bk[BCH];
#pragma unroll
    for (int j=0;j<BCH;j++){ int c = tid + j*256; br[j]=c>>2; bk[j]=(c&3)*8; }

    f32x4 acc[MREP][NREP];
#pragma unroll
    for (int m=0;m<MREP;m++)
#pragma unroll
        for (int n=0;n<NREP;n++) acc[m][n] = (f32x4)0.f;

    bf16x8 rah[ACH], ral[ACH], rbh[BCH], rbl[BCH];

    auto load_tile = [&](int kt){
#pragma unroll
        for (int j=0;j<ACH;j++){
            long o = (long)(m0+ar[j])*lda + kt + ak[j];
            rah[j] = *reinterpret_cast<const bf16x8*>(&Agh[o]);
            ral[j] = *reinterpret_cast<const bf16x8*>(&Agl[o]);
        }
#pragma unroll
        for (int j=0;j<BCH;j++){
            long o = (long)(n0+br[j])*ldb + kt + bk[j];
            rbh[j] = *reinterpret_cast<const bf16x8*>(&Bgh[o]);
            rbl[j] = *reinterpret_cast<const bf16x8*>(&Bgl[o]);
        }
    };

    load_tile(0);
    const int NK = K >> 5;
    for (int s=0; s<NK; ++s){
#pragma unroll
        for (int j=0;j<ACH;j++){
            *reinterpret_cast<bf16x8*>(&Ahs[ar[j]*KPAD + ak[j]]) = rah[j];
            *reinterpret_cast<bf16x8*>(&Als[ar[j]*KPAD + ak[j]]) = ral[j];
        }
#pragma unroll
        for (int j=0;j<BCH;j++){
            *reinterpret_cast<bf16x8*>(&Bhs[br[j]*KPAD + bk[j]]) = rbh[j];
            *reinterpret_cast<bf16x8*>(&Bls[br[j]*KPAD + bk[j]]) = rbl[j];
        }
        __syncthreads();
        if (s+1 < NK) load_tile((s+1) << 5);   // in flight during MFMAs below

        bf16x8 bh[NREP], bl[NREP];
#pragma unroll
        for (int n=0;n<NREP;n++){
            int row = wn*(BN/2) + n*16 + fr;
            bh[n] = *reinterpret_cast<const bf16x8*>(&Bhs[row*KPAD + fg*8]);
            bl[n] = *reinterpret_cast<const bf16x8*>(&Bls[row*KPAD + fg*8]);
        }
#pragma unroll
        for (int m=0;m<MREP;m++){
            int row = wm*(BM/2) + m*16 + fr;
            bf16x8 ah = *reinterpret_cast<const bf16x8*>(&Ahs[row*KPAD + fg*8]);
            bf16x8 al = *reinterpret_cast<const bf16x8*>(&Als[row*KPAD + fg*8]);
#pragma unroll
            for (int n=0;n<NREP;n++){
                acc[m][n] = __builtin_amdgcn_mfma_f32_16x16x32_bf16(al, bh[n], acc[m][n],0,0,0);
                acc[m][n] = __builtin_amdgcn_mfma_f32_16x16x32_bf16(ah, bl[n], acc[m][n],0,0,0);
                acc[m][n] = __builtin_amdgcn_mfma_f32_16x16x32_bf16(ah, bh[n], acc[m][n],0,0,0);
            }
        }
        __syncthreads();
    }

    // epilogue: C[row][col], row=m0+wm*BM/2+m*16+fg*4+q, col=n0+wn*BN/2+n*16+fr
#pragma unroll
    for (int m=0;m<MREP;m++)
#pragma unroll
      for (int n=0;n<NREP;n++)
#pragma unroll
        for (int q=0;q<4;q++){
            int row = m0 + wm*(BM/2) + m*16 + fg*4 + q;
            int col = n0 + wn*(BN/2) + n*16 + fr;
            float v = acc[m][n][q];
            if (EPI==0) {
                C[(long)row*ldc + col] = v;
            } else {
                short h = f2bf(v);
                Ch[(long)row*ldc + col] = h;
                Cl[(long)row*ldc + col] = f2bf(v - bf2f(h));
            }
        }
}

// ============================================================================
// fp32 tiled GEMM (small GEMMs), NT form.
// EPI: 0 = store, 1 = softplus(v + bias[n]) store, 2 = atomicAdd (split-K)
// ============================================================================
template<int BM,int BN,int BK,int TM,int TN,int EPI,bool SPLIT>
__global__ __launch_bounds__(256) void gemm_nt(
    const float* __restrict__ A, int lda,
    const float* __restrict__ Bmat, int ldb,
    float* __restrict__ C, int ldc,
    int M, int N, int K, int ksl,
    const float* __restrict__ bias)
{
    __shared__ float As[BK][BM+4];
    __shared__ float Bs[BK][BN+4];
    const int tid = threadIdx.x;
    const int tx = tid & 15, ty = tid >> 4;
    const int m0 = blockIdx.y * BM;
    const int n0 = blockIdx.x * BN;
    int k0 = 0, k1 = K;
    if (SPLIT) { k0 = blockIdx.z * ksl; k1 = k0 + ksl; }

    float acc[TM][TN];
#pragma unroll
    for (int i=0;i<TM;i++)
#pragma unroll
        for (int j=0;j<TN;j++) acc[i][j]=0.f;

    for (int kt=k0; kt<k1; kt+=BK) {
        constexpr int AV = BM*BK/4/256;
#pragma unroll
        for (int v=0; v<AV; ++v) {
            int idx = tid + v*256;
            int row = idx / (BK/4);
            int kq  = idx % (BK/4);
            float4 val = *reinterpret_cast<const float4*>(&A[(long)(m0+row)*lda + kt + kq*4]);
            As[kq*4+0][row]=val.x; As[kq*4+1][row]=val.y;
            As[kq*4+2][row]=val.z; As[kq*4+3][row]=val.w;
        }
        constexpr int BV = BN*BK/4/256;
#pragma unroll
        for (int v=0; v<BV; ++v) {
            int idx = tid + v*256;
            int row = idx / (BK/4);
            int kq  = idx % (BK/4);
            float4 val = *reinterpret_cast<const float4*>(&Bmat[(long)(n0+row)*ldb + kt + kq*4]);
            Bs[kq*4+0][row]=val.x; Bs[kq*4+1][row]=val.y;
            Bs[kq*4+2][row]=val.z; Bs[kq*4+3][row]=val.w;
        }
        __syncthreads();
#pragma unroll
        for (int k=0;k<BK;k++){
            float a[TM], b[TN];
#pragma unroll
            for (int i=0;i<TM;i+=4)
                *reinterpret_cast<float4*>(&a[i]) = *reinterpret_cast<const float4*>(&As[k][ty*TM+i]);
#pragma unroll
            for (int j=0;j<TN;j+=4)
                *reinterpret_cast<float4*>(&b[j]) = *reinterpret_cast<const float4*>(&Bs[k][tx*TN+j]);
#pragma unroll
            for (int i=0;i<TM;i++)
#pragma unroll
                for (int j=0;j<TN;j++) acc[i][j] = fmaf(a[i],b[j],acc[i][j]);
        }
        __syncthreads();
    }

#pragma unroll
    for (int i=0;i<TM;i++){
        int m = m0 + ty*TM + i;
        if (EPI==2) {
#pragma unroll
            for (int j=0;j<TN;j++) atomicAdd(&C[(long)m*ldc + n0 + tx*TN + j], acc[i][j]);
        } else {
#pragma unroll
            for (int j=0;j<TN;j+=4){
                int n = n0 + tx*TN + j;
                float4 o;
                float* po = &o.x;
#pragma unroll
                for (int q=0;q<4;q++){
                    float v = acc[i][j+q];
                    if (EPI==1) {
                        v += bias[n+q];
                        v = (v > 20.f) ? v : log1pf(__expf(v));
                    }
                    po[q] = v;
                }
                *reinterpret_cast<float4*>(&C[(long)m*ldc + n]) = o;
            }
        }
    }
}

// ============================================================================
// causal depthwise conv (k=4, left pad 3) + bias + silu; xz fp32 -> u fp32
// ============================================================================
__global__ __launch_bounds__(256) void conv_silu_k(
    const float* __restrict__ xz, const float* __restrict__ cw,
    const float* __restrict__ cb, float* __restrict__ u)
{
    int idx = blockIdx.x*256 + threadIdx.x;
    int d4  = idx & (DINNER/4 - 1);
    int row = idx >> 8;
    int t   = row & (LSEQ-1);

    float4 cbv = *reinterpret_cast<const float4*>(&cb[d4*4]);
    float acc[4] = {cbv.x, cbv.y, cbv.z, cbv.w};
    float4 cw0 = *reinterpret_cast<const float4*>(&cw[d4*16 + 0]);
    float4 cw1 = *reinterpret_cast<const float4*>(&cw[d4*16 + 4]);
    float4 cw2 = *reinterpret_cast<const float4*>(&cw[d4*16 + 8]);
    float4 cw3 = *reinterpret_cast<const float4*>(&cw[d4*16 +12]);
    const float* pw[4] = {&cw0.x, &cw1.x, &cw2.x, &cw3.x};

#pragma unroll
    for (int j=0;j<DCONV;j++){
        int tt = t - (DCONV-1) + j;
        if (tt < 0) continue;
        float4 xv = *reinterpret_cast<const float4*>(&xz[(long)(row-(DCONV-1)+j)*2*DINNER + d4*4]);
        acc[0] = fmaf(xv.x, pw[0][j], acc[0]);
        acc[1] = fmaf(xv.y, pw[1][j], acc[1]);
        acc[2] = fmaf(xv.z, pw[2][j], acc[2]);
        acc[3] = fmaf(xv.w, pw[3][j], acc[3]);
    }
    float4 o;
    o.x = acc[0]*sigmoid_(acc[0]);
    o.y = acc[1]*sigmoid_(acc[1]);
    o.z = acc[2]*sigmoid_(acc[2]);
    o.w = acc[3]*sigmoid_(acc[3]);
    *reinterpret_cast<float4*>(&u[(long)row*DINNER + d4*4]) = o;
}

// ============================================================================
// Chunked selective scan. delta lives in xz[:, 0:1024] (row stride 2048).
// ============================================================================
__global__ __launch_bounds__(256) void scan_phaseA(
    const float* __restrict__ xz, const float* __restrict__ u,
    const float* __restrict__ dbc, const float* __restrict__ Alog,
    float* __restrict__ hst, float* __restrict__ sd)
{
    __shared__ float Bsh[CHUNK*DSTATE];
    int bx = blockIdx.x;
    int dblk = bx & 3;
    int c    = (bx>>2) & (NCHUNK-1);
    int b    = bx >> 7;
    int d    = dblk*256 + threadIdx.x;

    for (int i = threadIdx.x; i < CHUNK*DSTATE; i += 256) {
        int tr = i >> 4, s = i & 15;
        Bsh[i] = dbc[(long)(b*LSEQ + c*CHUNK + tr)*64 + DTRANK + s];
    }
    __syncthreads();

    float As[DSTATE];
#pragma unroll
    for (int s=0;s<DSTATE;s++) As[s] = -__expf(Alog[d*DSTATE+s]);
    float h[DSTATE];
#pragma unroll
    for (int s=0;s<DSTATE;s++) h[s]=0.f;
    float sumd = 0.f;

    long baseU = (long)(b*LSEQ + c*CHUNK)*DINNER + d;
    long baseD = (long)(b*LSEQ + c*CHUNK)*2*DINNER + d;
    for (int tt=0; tt<CHUNK; ++tt) {
        float dt = xz[baseD + (long)tt*2*DINNER];
        float ut = u[baseU + (long)tt*DINNER];
        sumd += dt;
        float du = dt*ut;
#pragma unroll
        for (int s=0;s<DSTATE;s++)
            h[s] = fmaf(__expf(As[s]*dt), h[s], du*Bsh[tt*DSTATE+s]);
    }
    long ho = ((long)((b*NCHUNK + c)*DINNER) + d)*DSTATE;
#pragma unroll
    for (int s=0;s<DSTATE;s+=4)
        *reinterpret_cast<float4*>(&hst[ho+s]) = make_float4(h[s],h[s+1],h[s+2],h[s+3]);
    sd[(b*NCHUNK+c)*DINNER + d] = sumd;
}

__global__ __launch_bounds__(256) void scan_phaseB(
    const float* __restrict__ Alog, const float* __restrict__ sd,
    float* __restrict__ hst)
{
    int flat = blockIdx.x*256 + threadIdx.x;
    int s = flat & 15;
    int d = (flat >> 4) & (DINNER-1);
    int b = flat >> 14;
    float As = -__expf(Alog[d*DSTATE+s]);
    float H = 0.f;
    for (int c=0; c<NCHUNK; ++c) {
        long o = ((long)((b*NCHUNK+c)*DINNER)+d)*DSTATE + s;
        float hl  = hst[o];
        float sdc = sd[(b*NCHUNK+c)*DINNER + d];
        hst[o] = H;
        H = fmaf(__expf(As*sdc), H, hl);
    }
}

__global__ __launch_bounds__(256) void scan_phaseC(
    const float* __restrict__ xz, const float* __restrict__ u,
    const float* __restrict__ dbc, const float* __restrict__ Alog,
    const float* __restrict__ hst, const float* __restrict__ Dsk,
    short* __restrict__ yh, short* __restrict__ yl)
{
    __shared__ float Bsh[CHUNK*DSTATE];
    __shared__ float Csh[CHUNK*DSTATE];
    int bx = blockIdx.x;
    int dblk = bx & 3;
    int c    = (bx>>2) & (NCHUNK-1);
    int b    = bx >> 7;
    int d    = dblk*256 + threadIdx.x;

    for (int i = threadIdx.x; i < CHUNK*DSTATE; i += 256) {
        int tr = i >> 4, s = i & 15;
        long ro = (long)(b*LSEQ + c*CHUNK + tr)*64;
        Bsh[i] = dbc[ro + DTRANK + s];
        Csh[i] = dbc[ro + DTRANK + DSTATE + s];
    }
    __syncthreads();

    float As[DSTATE];
#pragma unroll
    for (int s=0;s<DSTATE;s++) As[s] = -__expf(Alog[d*DSTATE+s]);
    float h[DSTATE];
    long ho = ((long)((b*NCHUNK + c)*DINNER) + d)*DSTATE;
#pragma unroll
    for (int s=0;s<DSTATE;s+=4){
        float4 hv = *reinterpret_cast<const float4*>(&hst[ho+s]);
        h[s]=hv.x; h[s+1]=hv.y; h[s+2]=hv.z; h[s+3]=hv.w;
    }
    float Dd = Dsk[d];

    long baseU = (long)(b*LSEQ + c*CHUNK)*DINNER + d;
    long baseD = (long)(b*LSEQ + c*CHUNK)*2*DINNER + d;
    for (int tt=0; tt<CHUNK; ++tt) {
        float dt = xz[baseD + (long)tt*2*DINNER];
        float ut = u[baseU + (long)tt*DINNER];
        float du = dt*ut;
        float y = 0.f;
#pragma unroll
        for (int s=0;s<DSTATE;s++){
            h[s] = fmaf(__expf(As[s]*dt), h[s], du*Bsh[tt*DSTATE+s]);
            y = fmaf(h[s], Csh[tt*DSTATE+s], y);
        }
        y = fmaf(ut, Dd, y);
        float zv = xz[baseD + (long)tt*2*DINNER + DINNER];
        y *= zv * sigmoid_(zv);
        short hh = f2bf(y);
        yh[baseU + (long)tt*DINNER] = hh;
        yl[baseU + (long)tt*DINNER] = f2bf(y - bf2f(hh));
    }
}

// ============================================================================
extern "C" void kernel_launch(void* const* d_in, const int* in_sizes, int n_in,
                              void* d_out, int out_size, void* d_ws, size_t ws_size,
                              hipStream_t stream)
{
    const float* x_in = (const float*)d_in[0];
    const float* Wi   = (const float*)d_in[1];
    const float* cw   = (const float*)d_in[2];
    const float* cb   = (const float*)d_in[3];
    const float* Wx   = (const float*)d_in[4];
    const float* Wdt  = (const float*)d_in[5];
    const float* bdt  = (const float*)d_in[6];
    const float* Alog = (const float*)d_in[7];
    const float* Dsk  = (const float*)d_in[8];
    const float* Wo   = (const float*)d_in[9];
    float* out = (float*)d_out;

    // workspace layout: ~92 MB
    float* ws   = (float*)d_ws;
    float* xz   = ws;                        // 8388608 f (xin half becomes delta)
    float* u    = xz  + 8388608;             // 4194304 f
    float* dbc  = u   + 4194304;             // 262144 f
    float* hst  = dbc + 262144;              // 2097152 f
    float* sd   = hst + 2097152;             // 131072 f
    short* sp   = (short*)(sd + 131072);
    short* srch = sp;                        // 2097152 s (4096x512)
    short* srcl = srch + 2097152;
    short* wih  = srcl + 2097152;            // 1048576 s (2048x512)
    short* wil  = wih  + 1048576;
    short* woh  = wil  + 1048576;            // 524288 s (512x1024)
    short* wol  = woh  + 524288;
    short* yh   = wol  + 524288;             // 4194304 s (4096x1024)
    short* yl   = yh   + 4194304;

    // split layer-0 input
    split_k<<<NROWS*DMODEL/1024, 256, 0, stream>>>(x_in, srch, srcl);

    for (int l=0; l<NLAYER; ++l) {
        const float* Wi_l  = Wi  + (long)l*2*DINNER*DMODEL;
        const float* cw_l  = cw  + (long)l*DINNER*DCONV;
        const float* cb_l  = cb  + (long)l*DINNER;
        const float* Wx_l  = Wx  + (long)l*(DTRANK+2*DSTATE)*DINNER;
        const float* Wdt_l = Wdt + (long)l*DINNER*DTRANK;
        const float* bdt_l = bdt + (long)l*DINNER;
        const float* Al_l  = Alog+ (long)l*DINNER*DSTATE;
        const float* Dsk_l = Dsk + (long)l*DINNER;
        const float* Wo_l  = Wo  + (long)l*DMODEL*DINNER;

        // split weights for this layer
        split_k<<<2*DINNER*DMODEL/1024, 256, 0, stream>>>(Wi_l, wih, wil);
        split_k<<<DMODEL*DINNER/1024, 256, 0, stream>>>(Wo_l, woh, wol);

        // 1) xz = src @ Wi^T  (4096 x 2048, K=512)  128x64 tiles -> 1024 blocks
        gemm_bs_nt<128,64,0><<<dim3(2*DINNER/64, NROWS/128), 256, 0, stream>>>(
            srch, srcl, DMODEL, wih, wil, DMODEL, xz, 2*DINNER, nullptr, nullptr, DMODEL);

        // 2) u = silu(causal_dwconv(xin) + cb)
        conv_silu_k<<<NROWS*(DINNER/4)/256, 256, 0, stream>>>(xz, cw_l, cb_l, u);

        // 3) dbc = u @ Wx^T  (4096 x 64, K=1024) split-K=8 fp32
        hipMemsetAsync(dbc, 0, 262144*sizeof(float), stream);
        gemm_nt<64,64,16,4,4,2,true><<<dim3(1, NROWS/64, 8), 256, 0, stream>>>(
            u, DINNER, Wx_l, DINNER, dbc, 64, NROWS, 64, DINNER, DINNER/8, nullptr);

        // 4) delta = softplus(dt @ Wdt^T + bdt) -> overlaid on xz[:,0:1024]
        gemm_nt<128,64,16,8,4,1,false><<<dim3(DINNER/64, NROWS/128), 256, 0, stream>>>(
            dbc, 64, Wdt_l, DTRANK, xz, 2*DINNER, NROWS, DINNER, DTRANK, 0, bdt_l);

        // 5-7) chunked scan; phaseC writes gated y as split bf16 (yh/yl)
        scan_phaseA<<<B_SZ*NCHUNK*(DINNER/256), 256, 0, stream>>>(xz, u, dbc, Al_l, hst, sd);
        scan_phaseB<<<B_SZ*DINNER*DSTATE/256, 256, 0, stream>>>(Al_l, sd, hst);
        scan_phaseC<<<B_SZ*NCHUNK*(DINNER/256), 256, 0, stream>>>(xz, u, dbc, Al_l, hst, Dsk_l, yh, yl);

        // 8) out = y @ Wo^T  (4096 x 512, K=1024)  64x64 tiles -> 512 blocks
        if (l == NLAYER-1) {
            gemm_bs_nt<64,64,0><<<dim3(DMODEL/64, NROWS/64), 256, 0, stream>>>(
                yh, yl, DINNER, woh, wol, DINNER, out, DMODEL, nullptr, nullptr, DINNER);
        } else {
            gemm_bs_nt<64,64,1><<<dim3(DMODEL/64, NROWS/64), 256, 0, stream>>>(
                yh, yl, DINNER, woh, wol, DINNER, nullptr, DMODEL, srch, srcl, DINNER);
        }
    }
}